// Round 5
// baseline (220.475 us; speedup 1.0000x reference)
//
#include <hip/hip_runtime.h>
#include <hip/hip_bf16.h>
#include <math.h>

#define BATCH 128
#define LSEQ 24
#define NN 121      // nodes == d_model == out feature
#define SSZ 64      // state size
#define NSTEPS 6
#define BL 3072     // BATCH*LSEQ
#define HP 65       // padded inner dim for h/A in LDS (bank-conflict-free)

// ---------------- kernel 1: encoder -> feat[121] ----------------
__global__ __launch_bounds__(256) void enc_kernel(
    const float* __restrict__ x, const float* __restrict__ conv_w,
    const float* __restrict__ conv_b, const float* __restrict__ comp_w1,
    const float* __restrict__ comp_b1, const float* __restrict__ comp_w2,
    const float* __restrict__ comp_b2, float* __restrict__ feat_out)
{
    const int n = blockIdx.x;     // node
    const int tid = threadIdx.x;
    float acc[8] = {0.f,0.f,0.f,0.f,0.f,0.f,0.f,0.f};
    for (int i = tid; i < BL; i += 256) {
        const float xv = x[i * NN + n];
        const float4* w4 = reinterpret_cast<const float4*>(conv_w + i * 8);
        const float4 a = w4[0], b = w4[1];
        acc[0] += xv * a.x; acc[1] += xv * a.y; acc[2] += xv * a.z; acc[3] += xv * a.w;
        acc[4] += xv * b.x; acc[5] += xv * b.y; acc[6] += xv * b.z; acc[7] += xv * b.w;
    }
    __shared__ float red[256][9];   // pad 9: conflict-free
    __shared__ float hred[32];
    #pragma unroll
    for (int j = 0; j < 8; ++j) red[tid][j] = acc[j];
    __syncthreads();
    for (int s = 128; s > 0; s >>= 1) {
        if (tid < s) {
            #pragma unroll
            for (int j = 0; j < 8; ++j) red[tid][j] += red[tid + s][j];
        }
        __syncthreads();
    }
    if (tid < 32) {
        float g[8];
        #pragma unroll
        for (int j = 0; j < 8; ++j) g[j] = red[0][j] + conv_b[j];
        float hsum = comp_b1[tid];
        #pragma unroll
        for (int j = 0; j < 8; ++j)
            hsum += g[j] * (comp_w1[j * 32 + tid] + comp_w1[(j + 8) * 32 + tid]);
        const float hv = hsum > 0.f ? hsum : 0.01f * hsum;   // leaky
        hred[tid] = hv * comp_w2[tid];
    }
    __syncthreads();
    if (tid == 0) {
        float f = comp_b2[0];
        #pragma unroll
        for (int m = 0; m < 32; ++m) f += hred[m];
        feat_out[n] = f;
    }
}

// ---------------- kernel 2: sequential mamba chain (1 block) ----------------
__device__ __forceinline__ float softplus_f(float v) {
    return v > 20.f ? v : log1pf(expf(v));
}

// y[j] = act( sum_i in[i]*W[i*COLS+j] + bias[j] ), 512 threads, 4 row-slices
template<int ROWS, int COLS, int ACT>
__device__ __forceinline__ void matvec4(
    const float* __restrict__ W, const float* __restrict__ bias,
    const float* in, float* out, float* red, int tid)
{
    const int slice = tid >> 7;       // 0..3
    const int j = tid & 127;
    float a0 = 0.f, a1 = 0.f, a2 = 0.f, a3 = 0.f;
    if (j < COLS) {
        const int r0 = (ROWS * slice) >> 2;
        const int r1 = (ROWS * (slice + 1)) >> 2;
        int i = r0;
        #pragma unroll 2
        for (; i + 4 <= r1; i += 4) {
            a0 += in[i + 0] * W[(i + 0) * COLS + j];
            a1 += in[i + 1] * W[(i + 1) * COLS + j];
            a2 += in[i + 2] * W[(i + 2) * COLS + j];
            a3 += in[i + 3] * W[(i + 3) * COLS + j];
        }
        for (; i < r1; ++i) a0 += in[i] * W[i * COLS + j];
    }
    red[tid] = (a0 + a1) + (a2 + a3);
    __syncthreads();
    if (tid < COLS) {
        float s = red[tid] + red[tid + 128] + red[tid + 256] + red[tid + 384] + bias[tid];
        if (ACT == 1) s = fmaxf(s, 0.f);
        else if (ACT == 2) s = tanhf(s);
        out[tid] = s;
    }
    __syncthreads();
}

__global__ __launch_bounds__(512) void mamba_kernel(
    const float* __restrict__ adapter_w, const float* __restrict__ adapter_b,
    const float* __restrict__ ln_g, const float* __restrict__ ln_b,
    const float* __restrict__ lift_w1, const float* __restrict__ lift_b1,
    const float* __restrict__ lift_w2, const float* __restrict__ lift_b2,
    const float* __restrict__ net_w1, const float* __restrict__ net_b1,
    const float* __restrict__ net_w2, const float* __restrict__ net_b2,
    const float* __restrict__ fc1_w, const float* __restrict__ fc1_b,
    const float* __restrict__ fc2_w, const float* __restrict__ fc2_b,
    const float* __restrict__ fc3_w, const float* __restrict__ fc3_b,
    const float* __restrict__ Aw, const float* __restrict__ state_init,
    const float* __restrict__ fcout_w, const float* __restrict__ fcout_b,
    const float* __restrict__ feat_in, float* __restrict__ pred_out)
{
    __shared__ float cat[242];      // q in [0,121), lifted in [121,242)
    __shared__ float t1[128], t2[128], xts[128], deltas[128];
    __shared__ float Bms[64], Cms[64], outv[128], predv[128], zb[128], ftmp[128];
    __shared__ float red[512], redb[512];
    __shared__ float hs[NN * HP];
    __shared__ float Ash[NN * HP];
    __shared__ float scal[2];

    const int tid = threadIdx.x;

    // preload h (from state_init) and A into padded LDS
    for (int idx = tid; idx < NN * HP; idx += 512) {
        const int d = idx / HP, n = idx - d * HP;
        float hv = 0.f, av = 0.f;
        if (n < SSZ) { hv = state_init[d * SSZ + n]; av = Aw[d * SSZ + n]; }
        hs[idx] = hv; Ash[idx] = av;
    }
    if (tid < NN) ftmp[tid] = feat_in[tid];
    __syncthreads();

    // z = feat @ adapter_w + adapter_b
    matvec4<NN, NN, 0>(adapter_w, adapter_b, ftmp, zb, red, tid);

    // layernorm -> q (cat[0..121))
    {
        const float v = (tid < NN) ? zb[tid] : 0.f;
        red[tid] = v; redb[tid] = v * v;
        __syncthreads();
        for (int s = 256; s > 0; s >>= 1) {
            if (tid < s) { red[tid] += red[tid + s]; redb[tid] += redb[tid + s]; }
            __syncthreads();
        }
        if (tid == 0) {
            const float mu = red[0] / (float)NN;
            const float var = redb[0] / (float)NN - mu * mu;
            scal[0] = mu; scal[1] = 1.0f / sqrtf(var + 1e-5f);
        }
        __syncthreads();
        if (tid < NN) cat[tid] = (zb[tid] - scal[0]) * scal[1] * ln_g[tid] + ln_b[tid];
        __syncthreads();
    }

    // ev 0 = warmup (h only), ev 1..6 = steps (produce pred, feed back)
    for (int ev = 0; ev < 7; ++ev) {
        matvec4<NN, 128, 1>(lift_w1, lift_b1, cat, t1, red, tid);           // relu
        matvec4<128, NN, 2>(lift_w2, lift_b2, t1, cat + NN, red, tid);      // tanh -> lifted
        matvec4<242, 128, 1>(net_w1, net_b1, cat, t2, red, tid);            // relu
        matvec4<128, NN, 0>(net_w2, net_b2, t2, xts, red, tid);             // xt

        // fused delta / Bm / Cm (2 row-slices of 256 threads)
        {
            const int slice = tid >> 8;     // 0/1
            const int j = tid & 255;
            const float* Wp = nullptr; int col = 0, C = 0;
            if (j < 121)                { Wp = fc1_w; col = j;       C = 121; }
            else if (j >= 128 && j < 192) { Wp = fc2_w; col = j - 128; C = 64; }
            else if (j >= 192)          { Wp = fc3_w; col = j - 192; C = 64; }
            float a0 = 0.f, a1 = 0.f, a2 = 0.f, a3 = 0.f;
            if (Wp) {
                const int r0 = slice ? 60 : 0;
                const int r1 = slice ? 121 : 60;
                int i = r0;
                #pragma unroll 2
                for (; i + 4 <= r1; i += 4) {
                    a0 += xts[i + 0] * Wp[(i + 0) * C + col];
                    a1 += xts[i + 1] * Wp[(i + 1) * C + col];
                    a2 += xts[i + 2] * Wp[(i + 2) * C + col];
                    a3 += xts[i + 3] * Wp[(i + 3) * C + col];
                }
                for (; i < r1; ++i) a0 += xts[i] * Wp[i * C + col];
            }
            red[tid] = (a0 + a1) + (a2 + a3);
            __syncthreads();
            if (tid < 121)
                deltas[tid] = softplus_f(red[tid] + red[tid + 256] + fc1_b[tid]);
            else if (tid >= 128 && tid < 192)
                Bms[tid - 128] = red[tid] + red[tid + 256] + fc2_b[tid - 128];
            else if (tid >= 192 && tid < 256)
                Cms[tid - 192] = red[tid] + red[tid + 256] + fc3_b[tid - 192];
            __syncthreads();
        }

        // h update + out[d] = sum_n Cm[n]*h_new[d,n]
        {
            const int c = tid >> 7;       // n-chunk 0..3
            const int d = tid & 127;
            float acc = 0.f;
            if (d < NN) {
                const float dd = deltas[d];
                const float coef = xts[d] * dd;
                const int base = d * HP;
                #pragma unroll
                for (int k = 0; k < 16; ++k) {
                    const int n = (c << 4) + k;
                    const float s = dd * Ash[base + n];
                    const float cel = s > 0.f ? s : expm1f(s);   // celu, alpha=1
                    const float dAv = expf(-cel);
                    const float hn = dAv * hs[base + n] + coef * Bms[n];
                    hs[base + n] = hn;
                    acc += Cms[n] * hn;
                }
            }
            red[tid] = acc;
            __syncthreads();
            if (tid < NN) outv[tid] = red[tid] + red[tid + 128] + red[tid + 256] + red[tid + 384];
            __syncthreads();
        }

        if (ev > 0) {
            matvec4<NN, NN, 0>(fcout_w, fcout_b, outv, predv, red, tid);
            if (tid < NN) {
                const float p = predv[tid];
                cat[tid] = p;                          // q = pred
                pred_out[(ev - 1) * NN + tid] = p;
            }
            __syncthreads();
        }
    }
}

// ---------------- kernel 3: broadcast preds to (steps,b,l,m) ----------------
__global__ __launch_bounds__(128) void bcast_kernel(
    const float* __restrict__ pred, float* __restrict__ out)
{
    const int row = blockIdx.x;            // s*3072 + (b*24+l), 18432 rows
    const int s = row / BL;
    const int t = threadIdx.x;
    if (t < NN) out[row * NN + t] = pred[s * NN + t];
}

extern "C" void kernel_launch(void* const* d_in, const int* in_sizes, int n_in,
                              void* d_out, int out_size, void* d_ws, size_t ws_size,
                              hipStream_t stream)
{
    const float* x        = (const float*)d_in[0];
    const float* conv_w   = (const float*)d_in[3];
    const float* conv_b   = (const float*)d_in[4];
    const float* comp_w1  = (const float*)d_in[5];
    const float* comp_b1  = (const float*)d_in[6];
    const float* comp_w2  = (const float*)d_in[7];
    const float* comp_b2  = (const float*)d_in[8];
    const float* adapter_w= (const float*)d_in[9];
    const float* adapter_b= (const float*)d_in[10];
    const float* ln_g     = (const float*)d_in[11];
    const float* ln_b     = (const float*)d_in[12];
    const float* lift_w1  = (const float*)d_in[13];
    const float* lift_b1  = (const float*)d_in[14];
    const float* lift_w2  = (const float*)d_in[15];
    const float* lift_b2  = (const float*)d_in[16];
    const float* net_w1   = (const float*)d_in[17];
    const float* net_b1   = (const float*)d_in[18];
    const float* net_w2   = (const float*)d_in[19];
    const float* net_b2   = (const float*)d_in[20];
    const float* fc1_w    = (const float*)d_in[21];
    const float* fc1_b    = (const float*)d_in[22];
    const float* fc2_w    = (const float*)d_in[23];
    const float* fc2_b    = (const float*)d_in[24];
    const float* fc3_w    = (const float*)d_in[25];
    const float* fc3_b    = (const float*)d_in[26];
    const float* Aw       = (const float*)d_in[27];
    const float* state_in = (const float*)d_in[28];
    const float* fcout_w  = (const float*)d_in[29];
    const float* fcout_b  = (const float*)d_in[30];

    float* ws   = (float*)d_ws;
    float* feat = ws;          // 121 floats
    float* pred = ws + 128;    // 6*121 floats

    enc_kernel<<<NN, 256, 0, stream>>>(x, conv_w, conv_b, comp_w1, comp_b1,
                                       comp_w2, comp_b2, feat);
    mamba_kernel<<<1, 512, 0, stream>>>(adapter_w, adapter_b, ln_g, ln_b,
        lift_w1, lift_b1, lift_w2, lift_b2, net_w1, net_b1, net_w2, net_b2,
        fc1_w, fc1_b, fc2_w, fc2_b, fc3_w, fc3_b, Aw, state_in,
        fcout_w, fcout_b, feat, pred);
    bcast_kernel<<<NSTEPS * BL, 128, 0, stream>>>(pred, (float*)d_out);
}